// Round 6
// baseline (576.818 us; speedup 1.0000x reference)
//
#include <hip/hip_runtime.h>
#include <cstdint>

// Round 6: 2 adjacent float4s per thread (4-lane element groups) + nt hints.
//
// Evidence so far: traffic is minimal (FETCH == A exactly, B ~100% L3-hit,
// WRITE == O exactly), fully coalesced, VALU ~17%, LDS 0, occupancy ~72%.
// nt on all streams gave ~5% (R5). The harness's own fill kernel proves the
// memory system serves 10.2 B/cy/CU; we run at 7.6 B/cy/CU on mandatory
// traffic -> residual suspect is per-wave memory-queue turnover (each wave
// owned only 2 loads + 1 store).
//
// This version: thread t owns float4s {2t, 2t+1} of A, B, O.
//  - 4 independent nt loads (16 payload VGPRs: no R3-style load sinking),
//    no loop (no R1-style carried register reuse). Per-wave bytes double.
//  - One element's 32 floats now span 4 lanes x 8 floats; lane packs its
//    byte pre-shifted (byte base shift sb = 24 - 8*(t&3); float c of 8 is
//    IEEE bit sb+7-c), OR-butterfly is 2 DPP steps (xor1, xor2) per word.
//  - All 4 lanes redundantly multiply; each lane unpacks its own 8 bits ->
//    two coalesced nt float4 stores.

typedef float vfloat4 __attribute__((ext_vector_type(4)));

#define OR_DPP(v, ctrl) \
    ((v) | (uint32_t)__builtin_amdgcn_update_dpp(0, (int)(v), (ctrl), 0xF, 0xF, true))

#define DPP_QUAD_XOR1 0xB1  // quad_perm:[1,0,3,2]
#define DPP_QUAD_XOR2 0x4E  // quad_perm:[2,3,0,1]

__device__ __forceinline__ uint32_t pack4(vfloat4 v) {
    // MSB-first nibble: x->bit3, y->bit2, z->bit1, w->bit0
    return (v.x > 0.5f ? 8u : 0u) | (v.y > 0.5f ? 4u : 0u) |
           (v.z > 0.5f ? 2u : 0u) | (v.w > 0.5f ? 1u : 0u);
}

__device__ __forceinline__ vfloat4 unpack4(uint32_t wp, int s) {
    // bits s+3..s -> x..w
    vfloat4 o;
    o.x = (float)((wp >> (s + 3)) & 1u);
    o.y = (float)((wp >> (s + 2)) & 1u);
    o.z = (float)((wp >> (s + 1)) & 1u);
    o.w = (float)((wp >> s) & 1u);
    return o;
}

__global__ __launch_bounds__(256) void spikefp32mul_kernel(
    const vfloat4* __restrict__ A4, const vfloat4* __restrict__ B4,
    vfloat4* __restrict__ O4, int n8)
{
    int t = blockIdx.x * blockDim.x + threadIdx.x;
    if (t >= n8) return;

    const int g = 2 * t;

    // 4 independent 16B nt loads, distinct registers.
    vfloat4 a0 = __builtin_nontemporal_load(&A4[g]);
    vfloat4 a1 = __builtin_nontemporal_load(&A4[g + 1]);
    vfloat4 b0 = __builtin_nontemporal_load(&B4[g]);
    vfloat4 b1 = __builtin_nontemporal_load(&B4[g + 1]);

    // Thread holds floats f = 8t + c, c=0..7; bit j = 8*(t&3)+c; IEEE bit
    // 31-j. Byte base shift:
    const int sb = 24 - 8 * (t & 3);

    uint32_t wa = ((pack4(a0) << 4) | pack4(a1)) << sb;
    uint32_t wb = ((pack4(b0) << 4) | pack4(b1)) << sb;

    // OR-butterfly across the 4 lanes of this element group (VALU DPP only).
    wa = OR_DPP(wa, DPP_QUAD_XOR1);
    wb = OR_DPP(wb, DPP_QUAD_XOR1);
    wa = OR_DPP(wa, DPP_QUAD_XOR2);
    wb = OR_DPP(wb, DPP_QUAD_XOR2);

    float p = __uint_as_float(wa) * __uint_as_float(wb);  // IEEE fp32 mul, RNE
    uint32_t wp = __float_as_uint(p);

    __builtin_nontemporal_store(unpack4(wp, sb + 4), &O4[g]);
    __builtin_nontemporal_store(unpack4(wp, sb), &O4[g + 1]);
}

extern "C" void kernel_launch(void* const* d_in, const int* in_sizes, int n_in,
                              void* d_out, int out_size, void* d_ws, size_t ws_size,
                              hipStream_t stream) {
    const vfloat4* A4 = (const vfloat4*)d_in[0];
    const vfloat4* B4 = (const vfloat4*)d_in[1];
    vfloat4* O4 = (vfloat4*)d_out;

    int n4 = in_sizes[0] / 4;   // 16,777,216 float4s
    int n8 = n4 >> 1;           // 8,388,608 threads; 32768 blocks of 256
    const int block = 256;
    const int grid = (n8 + block - 1) / block;
    spikefp32mul_kernel<<<grid, block, 0, stream>>>(A4, B4, O4, n8);
}

// Round 7
// 552.065 us; speedup vs baseline: 1.0448x; 1.0448x over previous
//
#include <hip/hip_runtime.h>
#include <cstdint>

// FINAL (revert to Round-5 best, 555.8us bench): Round-0 structure
// (1 element-group per thread, fully coalesced, DPP OR-butterfly) +
// non-temporal hints on all three streams.
//
// Session evidence:
//  - Traffic is minimal: FETCH == A exactly (B is ~100% L3-resident from the
//    harness restore), WRITE == O exactly. Fully coalesced dwordx4 both ways.
//  - DPP butterfly keeps cross-lane work on the VALU pipe (no LDS, no
//    lgkmcnt); SQ_LDS_BANK_CONFLICT == 0.
//  - nt on A/O stops zero-reuse streams churning the L3 set that serves B:
//    +5% (R5), the only post-baseline win.
//  - MLP-increasing variants (grid-stride loop R1; 4 disjoint streams R3)
//    and wave-fattening (2 float4/thread R6) all regressed or were neutral:
//    the kernel sits at ~82% of the copy ceiling for its mandatory 804 MiB
//    of CU-side traffic; the residual is mixed-stream fabric efficiency.
//
// Scheme: lane i loads float4 #i; one element's 32 spike floats span 8
// consecutive lanes (4 floats/lane). Each lane packs its 4 bits pre-shifted
// into IEEE MSB-first position (sb = 28 - 4*(g&7)); 3-step OR-butterfly
// (quad_perm xor1, quad_perm xor2, row_half_mirror) gives every lane the
// full word. All 8 lanes redundantly do the IEEE fp32 multiply (RNE,
// subnormal-correct in HW); each lane unpacks its own 4 output bits.

typedef float vfloat4 __attribute__((ext_vector_type(4)));

#define OR_DPP(v, ctrl) \
    ((v) | (uint32_t)__builtin_amdgcn_update_dpp(0, (int)(v), (ctrl), 0xF, 0xF, true))

#define DPP_QUAD_XOR1 0xB1        // quad_perm:[1,0,3,2]
#define DPP_QUAD_XOR2 0x4E        // quad_perm:[2,3,0,1]
#define DPP_ROW_HALF_MIRROR 0x141 // lane i -> 7-i within each 8-lane group

__global__ __launch_bounds__(256) void spikefp32mul_kernel(
    const vfloat4* __restrict__ A4, const vfloat4* __restrict__ B4,
    vfloat4* __restrict__ O4, int n4)
{
    int g = blockIdx.x * blockDim.x + threadIdx.x;
    if (g >= n4) return;

    vfloat4 a = __builtin_nontemporal_load(&A4[g]);
    vfloat4 b = __builtin_nontemporal_load(&B4[g]);

    // float index f = 4g + c belongs to element g/8, bit j = f%32 = 4*(g&7)+c,
    // which is IEEE bit 31-j. Nibble base shift:
    const int sb = 28 - 4 * (g & 7);

    uint32_t wa = ((a.x > 0.5f ? 8u : 0u) | (a.y > 0.5f ? 4u : 0u) |
                   (a.z > 0.5f ? 2u : 0u) | (a.w > 0.5f ? 1u : 0u)) << sb;
    uint32_t wb = ((b.x > 0.5f ? 8u : 0u) | (b.y > 0.5f ? 4u : 0u) |
                   (b.z > 0.5f ? 2u : 0u) | (b.w > 0.5f ? 1u : 0u)) << sb;

    // OR-butterfly across the 8 lanes of this element group (VALU DPP only).
    wa = OR_DPP(wa, DPP_QUAD_XOR1);
    wb = OR_DPP(wb, DPP_QUAD_XOR1);
    wa = OR_DPP(wa, DPP_QUAD_XOR2);
    wb = OR_DPP(wb, DPP_QUAD_XOR2);
    wa = OR_DPP(wa, DPP_ROW_HALF_MIRROR);
    wb = OR_DPP(wb, DPP_ROW_HALF_MIRROR);

    float p = __uint_as_float(wa) * __uint_as_float(wb);  // IEEE fp32 mul, RNE
    uint32_t wp = __float_as_uint(p);

    vfloat4 o;
    o.x = (float)((wp >> (sb + 3)) & 1u);
    o.y = (float)((wp >> (sb + 2)) & 1u);
    o.z = (float)((wp >> (sb + 1)) & 1u);
    o.w = (float)((wp >> sb) & 1u);
    __builtin_nontemporal_store(o, &O4[g]);
}

extern "C" void kernel_launch(void* const* d_in, const int* in_sizes, int n_in,
                              void* d_out, int out_size, void* d_ws, size_t ws_size,
                              hipStream_t stream) {
    const vfloat4* A4 = (const vfloat4*)d_in[0];
    const vfloat4* B4 = (const vfloat4*)d_in[1];
    vfloat4* O4 = (vfloat4*)d_out;

    int n4 = in_sizes[0] / 4;   // 16,777,216 float4s; 65536 blocks of 256
    const int block = 256;
    const int grid = (n4 + block - 1) / block;
    spikefp32mul_kernel<<<grid, block, 0, stream>>>(A4, B4, O4, n4);
}